// Round 4
// baseline (1855.802 us; speedup 1.0000x reference)
//
#include <hip/hip_runtime.h>

#define DEV __device__ __forceinline__

typedef short s16x8 __attribute__((ext_vector_type(8)));
typedef float f32x4 __attribute__((ext_vector_type(4)));
typedef _Float16 h16x2 __attribute__((ext_vector_type(2)));
typedef unsigned short u16;

constexpr int Wn = 128;    // words
constexpr int Pn = 4096;   // phrases
constexpr int Rn = 8192;   // relations
constexpr int Hn = 1024;   // hidden

DEV float b2f(u16 u) { union { unsigned i; float f; } x; x.i = (unsigned)u << 16; return x.f; }
DEV u16 f2b(float f) {
  union { float f; unsigned i; } x; x.f = f;
  unsigned r = x.i + 0x7FFF + ((x.i >> 16) & 1);   // RNE
  return (u16)(r >> 16);
}
DEV float leaky(float x) { return x >= 0.f ? x : 0.01f * x; }

DEV void load_lds16(const void* g, void* l) {
  __builtin_amdgcn_global_load_lds(
      (const __attribute__((address_space(1))) void*)g,
      (__attribute__((address_space(3))) void*)l, 16, 0, 0);
}

DEV float wred_sum(float v) {
  #pragma unroll
  for (int m = 1; m < 64; m <<= 1) v += __shfl_xor(v, m, 64);
  return v;
}
DEV float wred_max(float v) {
  #pragma unroll
  for (int m = 1; m < 64; m <<= 1) v = fmaxf(v, __shfl_xor(v, m, 64));
  return v;
}

// f32 -> bf16 row-block convert. Row length is always 1024 elements here;
// each thread converts 8 elements: g>>7 = row, (g&127)*8 = col.
__global__ __launch_bounds__(256) void k_cvt(
    const float* __restrict__ src, int sld, u16* __restrict__ dst)
{
  int g = blockIdx.x * 256 + threadIdx.x;
  int row = g >> 7, c = (g & 127) * 8;
  const float* s = src + (size_t)row * sld + c;
  float4 a = *(const float4*)s;
  float4 b = *(const float4*)(s + 4);
  ushort4 lo = {f2b(a.x), f2b(a.y), f2b(a.z), f2b(a.w)};
  ushort4 hi = {f2b(b.x), f2b(b.y), f2b(b.z), f2b(b.w)};
  *(ushort4*)(dst + (size_t)row * 1024 + c) = lo;
  *(ushort4*)(dst + (size_t)row * 1024 + c + 4) = hi;
}

// ---------------------------------------------------------------------------
// GEMM (B^T form): C[M,N] = epilogue( A[M,K] @ B[N,K]^T ).  A,B bf16 row-major.
// 128x128 tile, BK=64, 256 threads (4 waves, each 64x64 via 4x4 16x16x32 MFMA).
// LDS XOR-swizzled (byte ^ ((row&7)<<4)) via pre-swizzled global source so
// global_load_lds keeps its linear dest. bias/res are f32. res may alias C
// (in-place f32 add): each element read+written by exactly one thread.
// DUAL additionally writes a bf16 copy to C16.
// ---------------------------------------------------------------------------
template<bool OUTF32, bool ACT, bool BIAS, bool RES, bool DUAL>
__global__ __launch_bounds__(256) void k_gemm_bt(
    const u16* __restrict__ A, int lda,
    const u16* __restrict__ B, int ldb,
    void* Cp, int ldc,
    const float* __restrict__ bias,
    const float* res, int ldr,
    u16* C16,
    float alpha, int K)
{
  __shared__ __align__(16) char sm[32768];
  char* As = sm;
  char* Bs = sm + 16384;
  const int tid = threadIdx.x;
  const int lane = tid & 63, w = tid >> 6;
  const int m0 = blockIdx.y * 128, n0 = blockIdx.x * 128;
  const int wr = (w >> 1) * 64, wc = (w & 1) * 64;
  const int r_lo = lane & 15, kq = lane >> 4;

  f32x4 acc[4][4];
  #pragma unroll
  for (int i = 0; i < 4; ++i)
    #pragma unroll
    for (int j = 0; j < 4; ++j) acc[i][j] = (f32x4){0.f, 0.f, 0.f, 0.f};

  for (int kt = 0; kt < K; kt += 64) {
    if (kt) __syncthreads();
    #pragma unroll
    for (int i = 0; i < 4; ++i) {        // stage A (4 x 4KB)
      int f = i * 4096 + tid * 16;
      int row = f >> 7, colb = f & 127;
      int scol = colb ^ ((row & 7) << 4);
      const char* src = (const char*)(A + (size_t)(m0 + row) * lda + kt) + scol;
      load_lds16(src, As + i * 4096 + w * 1024);
    }
    #pragma unroll
    for (int i = 0; i < 4; ++i) {        // stage B
      int f = i * 4096 + tid * 16;
      int row = f >> 7, colb = f & 127;
      int scol = colb ^ ((row & 7) << 4);
      const char* src = (const char*)(B + (size_t)(n0 + row) * ldb + kt) + scol;
      load_lds16(src, Bs + i * 4096 + w * 1024);
    }
    __syncthreads();                     // compiler drains vmcnt before barrier
    #pragma unroll
    for (int ks = 0; ks < 2; ++ks) {
      s16x8 af[4], bfr[4];
      const int kb = ks * 64 + kq * 16;
      #pragma unroll
      for (int mi = 0; mi < 4; ++mi) {
        int row = wr + mi * 16 + r_lo;
        af[mi] = *(const s16x8*)(As + row * 128 + (kb ^ ((row & 7) << 4)));
      }
      #pragma unroll
      for (int ni = 0; ni < 4; ++ni) {
        int row = wc + ni * 16 + r_lo;
        bfr[ni] = *(const s16x8*)(Bs + row * 128 + (kb ^ ((row & 7) << 4)));
      }
      #pragma unroll
      for (int mi = 0; mi < 4; ++mi)
        #pragma unroll
        for (int ni = 0; ni < 4; ++ni)
          acc[mi][ni] = __builtin_amdgcn_mfma_f32_16x16x32_bf16(af[mi], bfr[ni], acc[mi][ni], 0, 0, 0);
    }
  }

  // epilogue: C/D layout col = lane&15, row = (lane>>4)*4 + j
  #pragma unroll
  for (int mi = 0; mi < 4; ++mi) {
    #pragma unroll
    for (int ni = 0; ni < 4; ++ni) {
      #pragma unroll
      for (int j = 0; j < 4; ++j) {
        int r = m0 + wr + mi * 16 + kq * 4 + j;
        int c = n0 + wc + ni * 16 + r_lo;
        float v = acc[mi][ni][j] * alpha;
        if (BIAS) v += bias[c];
        if (RES)  v += res[(size_t)r * ldr + c];
        if (ACT)  v = leaky(v);
        if (OUTF32) ((float*)Cp)[(size_t)r * ldc + c] = v;
        else        ((u16*)Cp)[(size_t)r * ldc + c] = f2b(v);
        if (DUAL)   C16[(size_t)r * ldc + c] = f2b(v);
      }
    }
  }
}

// ---------------------------------------------------------------------------
// Bidirectional GRU scan. 16 blocks per direction; block b owns h-slice
// j in [32b, 32b+32), i.e. gate rows {32b+j, 512+32b+j, 1024+32b+j}:
// 96x512 weights (f16) in LDS (96KB; total LDS ~101KB -> 1 block/CU).
// Per step: wave-per-gate fdot2 dots -> pointwise update (gi read from L2)
// -> publish h-slice + release flag; spin-acquire on step counter == 16.
// ---------------------------------------------------------------------------
__global__ __launch_bounds__(256) void k_gru(
    const float* __restrict__ w_hh_f, const float* __restrict__ w_hh_b,
    const float* __restrict__ b_hh_f, const float* __restrict__ b_hh_b,
    const float* __restrict__ gi_f, const float* __restrict__ gi_b,
    float* __restrict__ Hs, float* __restrict__ ctx, int* __restrict__ flags)
{
  __shared__ __align__(16) u16 wlds[96 * 512];   // f16 bits
  __shared__ float bh[96];
  __shared__ float hfull[512];
  __shared__ float ghl[96];

  const int bid = blockIdx.x;
  const int dir = bid >> 4;
  const int b   = bid & 15;
  const int tid = threadIdx.x;
  const int lane = tid & 63, wv = tid >> 6;

  const float* w_hh = dir ? w_hh_b : w_hh_f;
  const float* b_hh = dir ? b_hh_b : b_hh_f;
  const float* gi = dir ? gi_b : gi_f;
  float* myHs = Hs + (size_t)dir * 128 * 512;
  int* myflags = flags + dir * 128;

  for (int idx = tid; idx < 96 * 128; idx += 256) {   // weights f32 -> f16 LDS
    int gl = idx >> 7;
    int kc = (idx & 127) << 2;
    int g = 32 * b + (gl & 31) + ((gl >> 5) << 9);
    float4 wv4 = *(const float4*)(w_hh + (size_t)g * 512 + kc);
    u16 dst[4];
    _Float16 h0 = (_Float16)wv4.x; __builtin_memcpy(&dst[0], &h0, 2);
    _Float16 h1 = (_Float16)wv4.y; __builtin_memcpy(&dst[1], &h1, 2);
    _Float16 h2 = (_Float16)wv4.z; __builtin_memcpy(&dst[2], &h2, 2);
    _Float16 h3 = (_Float16)wv4.w; __builtin_memcpy(&dst[3], &h3, 2);
    *(uint2*)(wlds + gl * 512 + kc) = *(uint2*)dst;
  }
  if (tid < 96) {
    int g = 32 * b + (tid & 31) + ((tid >> 5) << 9);
    bh[tid] = b_hh[g];
  }
  for (int i = tid; i < 512; i += 256) hfull[i] = 0.f;
  __syncthreads();

  h16x2 hh[4];
  #pragma unroll
  for (int i = 0; i < 4; ++i) { hh[i][0] = (_Float16)0.f; hh[i][1] = (_Float16)0.f; }

  for (int sidx = 0; sidx < 128; ++sidx) {
    const int t = dir ? (127 - sidx) : sidx;
    for (int gg = 0; gg < 24; ++gg) {        // wave wv handles gates wv*24..+24
      int gl = wv * 24 + gg;
      const h16x2* wp = (const h16x2*)(wlds + gl * 512 + lane * 8);
      float pp = 0.f;
      pp = __builtin_amdgcn_fdot2(wp[0], hh[0], pp, false);
      pp = __builtin_amdgcn_fdot2(wp[1], hh[1], pp, false);
      pp = __builtin_amdgcn_fdot2(wp[2], hh[2], pp, false);
      pp = __builtin_amdgcn_fdot2(wp[3], hh[3], pp, false);
      pp = wred_sum(pp);
      if (lane == 0) ghl[gl] = pp;
    }
    __syncthreads();
    if (tid < 32) {
      int j = tid, jg = 32 * b + j;
      float gir = gi[t * 1536 + jg];
      float giz = gi[t * 1536 + 512 + jg];
      float gin = gi[t * 1536 + 1024 + jg];
      float ghr = ghl[j] + bh[j];
      float ghz = ghl[j + 32] + bh[j + 32];
      float ghn = ghl[j + 64] + bh[j + 64];
      float rr = 1.f / (1.f + __expf(-(gir + ghr)));
      float zz = 1.f / (1.f + __expf(-(giz + ghz)));
      float nn = tanhf(gin + rr * ghn);
      float h2v = (1.f - zz) * nn + zz * hfull[jg];
      myHs[sidx * 512 + jg] = h2v;
      if (sidx == 0)   ctx[(dir ? 1536 : 0)    + jg] = h2v;
      if (sidx == 127) ctx[(dir ? 512  : 1024) + jg] = h2v;
    }
    __syncthreads();
    if (tid == 0) {
      __threadfence();
      __hip_atomic_fetch_add(myflags + sidx, 1, __ATOMIC_RELEASE, __HIP_MEMORY_SCOPE_AGENT);
    }
    if (sidx < 127) {
      if (tid == 0) {
        while (__hip_atomic_load(myflags + sidx, __ATOMIC_ACQUIRE, __HIP_MEMORY_SCOPE_AGENT) < 16)
          __builtin_amdgcn_s_sleep(2);
      }
      __syncthreads();
      for (int i = tid; i < 512; i += 256) hfull[i] = myHs[sidx * 512 + i];
      __syncthreads();
      #pragma unroll
      for (int i = 0; i < 4; ++i) {
        hh[i][0] = (_Float16)hfull[lane * 8 + 2 * i];
        hh[i][1] = (_Float16)hfull[lane * 8 + 2 * i + 1];
      }
    }
  }
}

// ---------------------------------------------------------------------------
// small kernels
// ---------------------------------------------------------------------------
__global__ __launch_bounds__(256) void k_softmax1(
    const float* __restrict__ scores, const int* __restrict__ conn, u16* __restrict__ attw)
{
  int p = blockIdx.x * 4 + (threadIdx.x >> 6);
  int lane = threadIdx.x & 63;
  float v0 = scores[(size_t)p * 128 + lane];
  float v1 = scores[(size_t)p * 128 + 64 + lane];
  int m0 = conn[(size_t)p * 128 + lane];
  int m1 = conn[(size_t)p * 128 + 64 + lane];
  float x0 = m0 > 0 ? v0 : -INFINITY;
  float x1 = m1 > 0 ? v1 : -INFINITY;
  float mx = wred_max(fmaxf(x0, x1));
  if (!(mx > -INFINITY)) mx = 0.f;
  float e0 = m0 > 0 ? __expf(v0 - mx) : 0.f;
  float e1 = m1 > 0 ? __expf(v1 - mx) : 0.f;
  float s = wred_sum(e0 + e1);
  float inv = 1.f / (s + 1e-6f);
  attw[(size_t)p * 128 + lane] = f2b(e0 * inv);
  attw[(size_t)p * 128 + 64 + lane] = f2b(e1 * inv);
}

__global__ __launch_bounds__(256) void k_transpose(const u16* __restrict__ in, u16* __restrict__ out)
{
  int idx = blockIdx.x * 256 + threadIdx.x;   // over 128*1024
  int r = idx >> 10, c = idx & 1023;
  out[c * 128 + r] = in[idx];
}

// G[i] = src16[idxs[i]] : bf16 row gather (1024 wide), 4096 rows.
__global__ __launch_bounds__(256) void k_gather(const int* __restrict__ idxs,
    const u16* __restrict__ src, u16* __restrict__ G)
{
  int g = blockIdx.x * 256 + threadIdx.x;    // over 4096*128 16B-chunks
  int row = g >> 7, c16 = g & 127;
  int sidx = idxs[row];
  *(uint4*)(G + (size_t)row * Hn + c16 * 8) =
      *(const uint4*)(src + (size_t)sidx * Hn + c16 * 8);
}

__global__ __launch_bounds__(256) void k_cvec(const float* __restrict__ att1W,
    const float* __restrict__ att1b, const float* __restrict__ ctx, float* __restrict__ cvec)
{
  int i = blockIdx.x * 4 + (threadIdx.x >> 6);
  int lane = threadIdx.x & 63;
  const float* wrow = att1W + (size_t)i * 4096 + 2048 + lane * 32;
  const float* cp = ctx + lane * 32;
  float acc = 0.f;
  #pragma unroll
  for (int k = 0; k < 32; ++k) acc += wrow[k] * cp[k];
  acc = wred_sum(acc);
  if (lane == 0) cvec[i] = acc + att1b[i];
}

// edge scores for relation chunk [cb, cb+rows): edges e=cb+i and e=Rn+cb+i.
__global__ __launch_bounds__(256) void k_edge_s(const int* __restrict__ rcm,
    const u16* __restrict__ U1, const u16* __restrict__ V1c, const float* __restrict__ cvec,
    const float* __restrict__ att2w, const float* __restrict__ att2b,
    float* __restrict__ sval, int cb, int rows)
{
  int idx = blockIdx.x * 4 + (threadIdx.x >> 6);   // [0, 2*rows)
  int lane = threadIdx.x & 63;
  int rL = idx < rows ? idx : idx - rows;
  int e = idx < rows ? cb + idx : Rn + cb + rL;
  int p = rcm[e];
  const u16* u = U1 + (size_t)p * Hn + lane * 16;
  const u16* v = V1c + (size_t)rL * Hn + lane * 16;
  const float* aw = att2w + lane * 16;
  const float* cv = cvec + lane * 16;
  float acc = 0.f;
  #pragma unroll
  for (int i = 0; i < 16; ++i) {
    float x = b2f(u[i]) + b2f(v[i]) + cv[i];
    acc += aw[i] * leaky(x);
  }
  acc = wred_sum(acc);
  if (lane == 0) sval[e] = acc + att2b[0];
}

__global__ __launch_bounds__(256) void k_cnt(const int* __restrict__ rcm, int* __restrict__ cnt)
{
  int e = blockIdx.x * 256 + threadIdx.x;
  if (e < Rn && rcm[e] == rcm[Rn + e]) return;   // duplicate cell: obj copy wins
  atomicAdd(cnt + rcm[e], 1);
}

__global__ __launch_bounds__(256) void k_scan(const int* __restrict__ cnt,
    int* __restrict__ offs, int* __restrict__ cursor)
{
  __shared__ int part[256];
  __shared__ int pscan[256];
  int tid = threadIdx.x;
  int loc[16]; int s = 0;
  #pragma unroll
  for (int i = 0; i < 16; ++i) { loc[i] = cnt[tid * 16 + i]; s += loc[i]; }
  part[tid] = s; __syncthreads();
  if (tid == 0) { int a = 0; for (int i = 0; i < 256; ++i) { pscan[i] = a; a += part[i]; } }
  __syncthreads();
  int base = pscan[tid];
  #pragma unroll
  for (int i = 0; i < 16; ++i) { offs[tid * 16 + i] = base; cursor[tid * 16 + i] = base; base += loc[i]; }
  if (tid == 255) offs[Pn] = base;
}

__global__ __launch_bounds__(256) void k_fill(const int* __restrict__ rcm,
    const float* __restrict__ sval, int* __restrict__ cursor,
    int* __restrict__ er, float* __restrict__ es)
{
  int e = blockIdx.x * 256 + threadIdx.x;
  if (e < Rn && rcm[e] == rcm[Rn + e]) return;
  int slot = atomicAdd(cursor + rcm[e], 1);
  er[slot] = e & (Rn - 1);
  es[slot] = sval[e];
}

__global__ __launch_bounds__(256) void k_att_apply(const int* __restrict__ offs,
    const int* __restrict__ er, const float* __restrict__ es,
    const float* __restrict__ urel, u16* __restrict__ pacc)
{
  int p = blockIdx.x;
  int tid = threadIdx.x;
  int beg = offs[p], end = offs[p + 1];
  float mx = -INFINITY;
  for (int i = beg; i < end; ++i) mx = fmaxf(mx, es[i]);
  float den = 1e-6f;
  for (int i = beg; i < end; ++i) den += __expf(es[i] - mx);
  float inv = 1.f / den;
  float a0 = 0.f, a1 = 0.f, a2 = 0.f, a3 = 0.f;
  int c0 = tid * 4;
  for (int i = beg; i < end; ++i) {
    float wgt = __expf(es[i] - mx) * inv;
    float4 q = *(const float4*)(urel + (size_t)er[i] * Hn + c0);
    a0 += wgt * q.x; a1 += wgt * q.y; a2 += wgt * q.z; a3 += wgt * q.w;
  }
  ushort4 ov; ov.x = f2b(a0); ov.y = f2b(a1); ov.z = f2b(a2); ov.w = f2b(a3);
  *(ushort4*)(pacc + (size_t)p * Hn + c0) = ov;
}

// ---------------------------------------------------------------------------
extern "C" void kernel_launch(void* const* d_in, const int* in_sizes, int n_in,
                              void* d_out, int out_size, void* d_ws, size_t ws_size,
                              hipStream_t stream)
{
  // ALL float tensors are float32 (reference dtype); bf16 only internally.
  const float* word_feat   = (const float*)d_in[0];
  const float* phrase_feat = (const float*)d_in[1];
  const float* rel_feat    = (const float*)d_in[2];
  const float* w_ih_f = (const float*)d_in[3];
  const float* w_hh_f = (const float*)d_in[4];
  const float* b_ih_f = (const float*)d_in[5];
  const float* b_hh_f = (const float*)d_in[6];
  const float* w_ih_b = (const float*)d_in[7];
  const float* w_hh_b = (const float*)d_in[8];
  const float* b_ih_b = (const float*)d_in[9];
  const float* b_hh_b = (const float*)d_in[10];
  const float* w2p_w_W = (const float*)d_in[11];
  const float* w2p_w_b = (const float*)d_in[12];
  const float* w2p_p_W = (const float*)d_in[13];
  const float* w2p_p_b = (const float*)d_in[14];
  const float* w2p_t_W = (const float*)d_in[15];
  const float* w2p_t_b = (const float*)d_in[16];
  const float* rel_W   = (const float*)d_in[17];
  const float* rel_b   = (const float*)d_in[18];
  const float* att1_W  = (const float*)d_in[19];
  const float* att1_b  = (const float*)d_in[20];
  const float* att2_W  = (const float*)d_in[21];
  const float* att2_b  = (const float*)d_in[22];
  const float* r2p_t_W = (const float*)d_in[23];
  const float* r2p_t_b = (const float*)d_in[24];
  const int* rcm  = (const int*)d_in[25];
  const int* conn = (const int*)d_in[26];

  float* out_word = (float*)d_out;
  float* out_phr  = out_word + (size_t)Wn * Hn;   // 4096x1024 f32
  float* out_urel = out_phr + (size_t)Pn * Hn;    // 8192x1024 f32

  // ---- workspace (~43 MB, static layout with phase-disjoint unions) ----
  char* ws = (char*)d_ws;
  size_t off = 0;
  auto alloc = [&](size_t bytes) -> char* {
    char* pptr = ws + off; off += (bytes + 255) & ~(size_t)255; return pptr;
  };
  int*   flags  = (int*)alloc(2 * 128 * 4 + Pn * 4);  // flags then cnt (one memset)
  int*   cnt    = flags + 2 * 128;
  float* ctx    = (float*)alloc(2048 * 4);
  float* cvec   = (float*)alloc(1024 * 4);
  int*   cursor = (int*)alloc(Pn * 4);
  int*   offs   = (int*)alloc((Pn + 1) * 4);
  int*   er     = (int*)alloc(2 * Rn * 4);
  float* es     = (float*)alloc(2 * Rn * 4);
  float* sval   = (float*)alloc(2 * Rn * 4);
  u16*   wf16   = (u16*)alloc((size_t)Wn * Hn * 2);       // 0.26MB
  u16*   wl     = (u16*)alloc((size_t)Wn * Hn * 2);       // 0.26MB
  u16*   upd16  = (u16*)alloc((size_t)Pn * Hn * 2);       // 8.39MB
  char*  RA     = alloc(16777216);                        // P3 / P5 union
  u16*   W1s    = (u16*)RA;                               // 2.10MB (P3)
  u16*   W2s    = (u16*)(RA + 2097152);                   // 2.10MB (P3)
  u16*   W3s    = (u16*)(RA + 4194304);                   // 2.10MB (P3)
  u16*   G      = (u16*)(RA + 6291456);                   // 8.39MB (P3)
  u16*   rf16c  = (u16*)(RA + 14680064);                  // 2.10MB (P3)
  u16*   pacc   = (u16*)RA;                               // 8.39MB (P5)
  u16*   r2pW16 = (u16*)(RA + 8388608);                   // 2.10MB (P5)
  u16*   A1p16  = (u16*)alloc(2097152);
  u16*   A1r16  = (u16*)alloc(2097152);
  u16*   U1     = (u16*)alloc((size_t)Pn * Hn * 2);       // 8.39MB
  u16*   urelc  = (u16*)alloc(2097152);
  u16*   V1c    = (u16*)alloc(2097152);

  // ---- d_out f32 regions as early-phase scratch ----
  char* phrB = (char*)out_phr;          // 16.78MB, free until upd write
  float* scores = (float*)phrB;                         // 2.10MB
  u16*   wih16f = (u16*)(phrB + 2097152);               // 3.15MB
  u16*   wih16b = (u16*)(phrB + 5242880);               // 3.15MB
  float* gi_f   = (float*)(phrB + 8388608);             // 0.79MB
  float* gi_b   = (float*)(phrB + 9175040);             // 0.79MB
  float* Hs     = (float*)(phrB + 9961472);             // 0.52MB
  char* urlB = (char*)out_urel;         // 33.55MB, free until urel writes
  u16*   pf16   = (u16*)urlB;                           // 8.39MB
  u16*   w2pw16 = (u16*)(urlB + 8388608);               // 2.10MB
  u16*   w2pp16 = (u16*)(urlB + 10485760);              // 2.10MB
  u16*   w2pt16 = (u16*)(urlB + 12582912);              // 2.10MB
  u16*   pl     = (u16*)(urlB + 14680064);              // 8.39MB
  u16*   aw     = (u16*)(urlB + 23068672);              // 8.39MB
  u16*   attw   = (u16*)(urlB + 31457280);              // 1.05MB
  u16*   wfT    = (u16*)(urlB + 32505856);              // 0.26MB

  (void)hipMemsetAsync(flags, 0, 2 * 128 * 4 + Pn * 4, stream);

  dim3 blk(256);

  // P1: GRU. Convert word/w_ih to bf16, gi GEMMs (f32 out), then the scan.
  k_cvt<<<64, blk, 0, stream>>>(word_feat, Hn, wf16);
  k_cvt<<<768, blk, 0, stream>>>(w_ih_f, Hn, wih16f);
  k_cvt<<<768, blk, 0, stream>>>(w_ih_b, Hn, wih16b);
  k_gemm_bt<true, false, true, false, false><<<dim3(12, 1), blk, 0, stream>>>(
      wf16, Hn, wih16f, Hn, gi_f, 1536, b_ih_f, nullptr, 0, nullptr, 1.f, Hn);
  k_gemm_bt<true, false, true, false, false><<<dim3(12, 1), blk, 0, stream>>>(
      wf16, Hn, wih16b, Hn, gi_b, 1536, b_ih_b, nullptr, 0, nullptr, 1.f, Hn);
  k_gru<<<32, blk, 0, stream>>>(w_hh_f, w_hh_b, b_hh_f, b_hh_b, gi_f, gi_b, Hs, ctx, flags);

  // P2: word->phrase attention; upd (f32 in out_phr + bf16 copy).
  k_cvt<<<2048, blk, 0, stream>>>(phrase_feat, Hn, pf16);
  k_cvt<<<512, blk, 0, stream>>>(w2p_w_W, Hn, w2pw16);
  k_cvt<<<512, blk, 0, stream>>>(w2p_p_W, Hn, w2pp16);
  k_cvt<<<512, blk, 0, stream>>>(w2p_t_W, Hn, w2pt16);
  k_gemm_bt<false, true, true, false, false><<<dim3(8, 1), blk, 0, stream>>>(
      wf16, Hn, w2pw16, Hn, wl, Hn, w2p_w_b, nullptr, 0, nullptr, 1.f, Hn);
  k_gemm_bt<false, true, true, false, false><<<dim3(8, 32), blk, 0, stream>>>(
      pf16, Hn, w2pp16, Hn, pl, Hn, w2p_p_b, nullptr, 0, nullptr, 1.f, Hn);
  k_gemm_bt<true, false, false, false, false><<<dim3(1, 32), blk, 0, stream>>>(
      pl, Hn, wl, Hn, scores, Wn, nullptr, nullptr, 0, nullptr, 0.03125f, Hn);
  k_softmax1<<<Pn / 4, blk, 0, stream>>>(scores, conn, attw);
  k_transpose<<<(Wn * Hn) / 256, blk, 0, stream>>>(wf16, wfT);
  k_gemm_bt<false, false, false, false, false><<<dim3(8, 32), blk, 0, stream>>>(
      attw, Wn, wfT, Wn, aw, Hn, nullptr, nullptr, 0, nullptr, 1.f, Wn);
  k_gemm_bt<true, false, true, true, true><<<dim3(8, 32), blk, 0, stream>>>(
      aw, Hn, w2pt16, Hn, out_phr, Hn, w2p_t_b, phrase_feat, Hn, upd16, 1.f, Hn);

  // P3: urel (f32 in out_urel) = rel_feat@W3' + upd[sub]@W1' + upd[obj]@W2' + b
  k_cvt<<<512, blk, 0, stream>>>(rel_W, 3 * Hn, W1s);
  k_cvt<<<512, blk, 0, stream>>>(rel_W + Hn, 3 * Hn, W2s);
  k_cvt<<<512, blk, 0, stream>>>(rel_W + 2 * Hn, 3 * Hn, W3s);
  for (int cb = 0; cb < Rn; cb += 1024) {
    k_cvt<<<512, blk, 0, stream>>>(rel_feat + (size_t)cb * Hn, Hn, rf16c);
    k_gemm_bt<true, false, true, false, false><<<dim3(8, 8), blk, 0, stream>>>(
        rf16c, Hn, W3s, Hn, out_urel + (size_t)cb * Hn, Hn, rel_b, nullptr, 0,
        nullptr, 1.f, Hn);
  }
  for (int h = 0; h < 2; ++h) {
    float* Ch = out_urel + (size_t)h * 4096 * Hn;
    k_gather<<<2048, blk, 0, stream>>>(rcm + h * 4096, upd16, G);
    k_gemm_bt<true, false, false, true, false><<<dim3(8, 32), blk, 0, stream>>>(
        G, Hn, W1s, Hn, Ch, Hn, nullptr, Ch, Hn, nullptr, 1.f, Hn);
    k_gather<<<2048, blk, 0, stream>>>(rcm + Rn + h * 4096, upd16, G);
    k_gemm_bt<true, false, false, true, false><<<dim3(8, 32), blk, 0, stream>>>(
        G, Hn, W2s, Hn, Ch, Hn, nullptr, Ch, Hn, nullptr, 1.f, Hn);
  }

  // P4: edge scores s = att2 . leaky(U1[p] + V1[r] + cvec)
  k_cvt<<<512, blk, 0, stream>>>(att1_W, 4 * Hn, A1p16);
  k_cvt<<<512, blk, 0, stream>>>(att1_W + Hn, 4 * Hn, A1r16);
  k_gemm_bt<false, false, false, false, false><<<dim3(8, 32), blk, 0, stream>>>(
      upd16, Hn, A1p16, Hn, U1, Hn, nullptr, nullptr, 0, nullptr, 1.f, Hn);
  k_cvec<<<256, blk, 0, stream>>>(att1_W, att1_b, ctx, cvec);
  for (int cb = 0; cb < Rn; cb += 1024) {
    k_cvt<<<512, blk, 0, stream>>>(out_urel + (size_t)cb * Hn, Hn, urelc);
    k_gemm_bt<false, false, false, false, false><<<dim3(8, 8), blk, 0, stream>>>(
        urelc, Hn, A1r16, Hn, V1c, Hn, nullptr, nullptr, 0, nullptr, 1.f, Hn);
    k_edge_s<<<512, blk, 0, stream>>>(rcm, U1, V1c, cvec, att2_W, att2_b, sval, cb, 1024);
  }

  // P5: CSR + masked softmax + att@urel; final residual GEMM in-place.
  k_cnt<<<(2 * Rn) / 256, blk, 0, stream>>>(rcm, cnt);
  k_scan<<<1, blk, 0, stream>>>(cnt, offs, cursor);
  k_fill<<<(2 * Rn) / 256, blk, 0, stream>>>(rcm, sval, cursor, er, es);
  k_att_apply<<<Pn, blk, 0, stream>>>(offs, er, es, out_urel, pacc);
  k_cvt<<<512, blk, 0, stream>>>(r2p_t_W, Hn, r2pW16);
  k_gemm_bt<true, false, true, true, false><<<dim3(8, 32), blk, 0, stream>>>(
      pacc, Hn, r2pW16, Hn, out_phr, Hn, r2p_t_b, out_phr, Hn, nullptr, 1.f, Hn);

  // word_feat passthrough (f32)
  (void)hipMemcpyAsync(out_word, word_feat, (size_t)Wn * Hn * 4,
                       hipMemcpyDeviceToDevice, stream);
}

// Round 5
// 1720.785 us; speedup vs baseline: 1.0785x; 1.0785x over previous
//
#include <hip/hip_runtime.h>

#define DEV __device__ __forceinline__

typedef short s16x8 __attribute__((ext_vector_type(8)));
typedef float f32x4 __attribute__((ext_vector_type(4)));
typedef _Float16 h16x2 __attribute__((ext_vector_type(2)));
typedef unsigned short u16;
typedef unsigned long long u64;

constexpr int Wn = 128;    // words
constexpr int Pn = 4096;   // phrases
constexpr int Rn = 8192;   // relations
constexpr int Hn = 1024;   // hidden

DEV float b2f(u16 u) { union { unsigned i; float f; } x; x.i = (unsigned)u << 16; return x.f; }
DEV u16 f2b(float f) {
  union { float f; unsigned i; } x; x.f = f;
  unsigned r = x.i + 0x7FFF + ((x.i >> 16) & 1);   // RNE
  return (u16)(r >> 16);
}
DEV float leaky(float x) { return x >= 0.f ? x : 0.01f * x; }

DEV void load_lds16(const void* g, void* l) {
  __builtin_amdgcn_global_load_lds(
      (const __attribute__((address_space(1))) void*)g,
      (__attribute__((address_space(3))) void*)l, 16, 0, 0);
}

DEV float wred_sum(float v) {
  #pragma unroll
  for (int m = 1; m < 64; m <<= 1) v += __shfl_xor(v, m, 64);
  return v;
}
DEV float wred_max(float v) {
  #pragma unroll
  for (int m = 1; m < 64; m <<= 1) v = fmaxf(v, __shfl_xor(v, m, 64));
  return v;
}

// f32 -> bf16 row-block convert. Row length is always 1024 elements here;
// each thread converts 8 elements: g>>7 = row, (g&127)*8 = col.
__global__ __launch_bounds__(256) void k_cvt(
    const float* __restrict__ src, int sld, u16* __restrict__ dst)
{
  int g = blockIdx.x * 256 + threadIdx.x;
  int row = g >> 7, c = (g & 127) * 8;
  const float* s = src + (size_t)row * sld + c;
  float4 a = *(const float4*)s;
  float4 b = *(const float4*)(s + 4);
  ushort4 lo = {f2b(a.x), f2b(a.y), f2b(a.z), f2b(a.w)};
  ushort4 hi = {f2b(b.x), f2b(b.y), f2b(b.z), f2b(b.w)};
  *(ushort4*)(dst + (size_t)row * 1024 + c) = lo;
  *(ushort4*)(dst + (size_t)row * 1024 + c + 4) = hi;
}

// ---------------------------------------------------------------------------
// GEMM (B^T form): C[M,N] = epilogue( A[M,K] @ B[N,K]^T ).  A,B bf16 row-major.
// 128x128 tile, BK=64, 256 threads (4 waves, each 64x64 via 4x4 16x16x32 MFMA).
// LDS XOR-swizzled (byte ^ ((row&7)<<4)) via pre-swizzled global source so
// global_load_lds keeps its linear dest. bias/res are f32. res may alias C
// (in-place f32 add): each element read+written by exactly one thread.
// DUAL additionally writes a bf16 copy to C16.
// ---------------------------------------------------------------------------
template<bool OUTF32, bool ACT, bool BIAS, bool RES, bool DUAL>
__global__ __launch_bounds__(256) void k_gemm_bt(
    const u16* __restrict__ A, int lda,
    const u16* __restrict__ B, int ldb,
    void* Cp, int ldc,
    const float* __restrict__ bias,
    const float* res, int ldr,
    u16* C16,
    float alpha, int K)
{
  __shared__ __align__(16) char sm[32768];
  char* As = sm;
  char* Bs = sm + 16384;
  const int tid = threadIdx.x;
  const int lane = tid & 63, w = tid >> 6;
  const int m0 = blockIdx.y * 128, n0 = blockIdx.x * 128;
  const int wr = (w >> 1) * 64, wc = (w & 1) * 64;
  const int r_lo = lane & 15, kq = lane >> 4;

  f32x4 acc[4][4];
  #pragma unroll
  for (int i = 0; i < 4; ++i)
    #pragma unroll
    for (int j = 0; j < 4; ++j) acc[i][j] = (f32x4){0.f, 0.f, 0.f, 0.f};

  for (int kt = 0; kt < K; kt += 64) {
    if (kt) __syncthreads();
    #pragma unroll
    for (int i = 0; i < 4; ++i) {        // stage A (4 x 4KB)
      int f = i * 4096 + tid * 16;
      int row = f >> 7, colb = f & 127;
      int scol = colb ^ ((row & 7) << 4);
      const char* src = (const char*)(A + (size_t)(m0 + row) * lda + kt) + scol;
      load_lds16(src, As + i * 4096 + w * 1024);
    }
    #pragma unroll
    for (int i = 0; i < 4; ++i) {        // stage B
      int f = i * 4096 + tid * 16;
      int row = f >> 7, colb = f & 127;
      int scol = colb ^ ((row & 7) << 4);
      const char* src = (const char*)(B + (size_t)(n0 + row) * ldb + kt) + scol;
      load_lds16(src, Bs + i * 4096 + w * 1024);
    }
    __syncthreads();                     // compiler drains vmcnt before barrier
    #pragma unroll
    for (int ks = 0; ks < 2; ++ks) {
      s16x8 af[4], bfr[4];
      const int kb = ks * 64 + kq * 16;
      #pragma unroll
      for (int mi = 0; mi < 4; ++mi) {
        int row = wr + mi * 16 + r_lo;
        af[mi] = *(const s16x8*)(As + row * 128 + (kb ^ ((row & 7) << 4)));
      }
      #pragma unroll
      for (int ni = 0; ni < 4; ++ni) {
        int row = wc + ni * 16 + r_lo;
        bfr[ni] = *(const s16x8*)(Bs + row * 128 + (kb ^ ((row & 7) << 4)));
      }
      #pragma unroll
      for (int mi = 0; mi < 4; ++mi)
        #pragma unroll
        for (int ni = 0; ni < 4; ++ni)
          acc[mi][ni] = __builtin_amdgcn_mfma_f32_16x16x32_bf16(af[mi], bfr[ni], acc[mi][ni], 0, 0, 0);
    }
  }

  // epilogue: C/D layout col = lane&15, row = (lane>>4)*4 + j
  #pragma unroll
  for (int mi = 0; mi < 4; ++mi) {
    #pragma unroll
    for (int ni = 0; ni < 4; ++ni) {
      #pragma unroll
      for (int j = 0; j < 4; ++j) {
        int r = m0 + wr + mi * 16 + kq * 4 + j;
        int c = n0 + wc + ni * 16 + r_lo;
        float v = acc[mi][ni][j] * alpha;
        if (BIAS) v += bias[c];
        if (RES)  v += res[(size_t)r * ldr + c];
        if (ACT)  v = leaky(v);
        if (OUTF32) ((float*)Cp)[(size_t)r * ldc + c] = v;
        else        ((u16*)Cp)[(size_t)r * ldc + c] = f2b(v);
        if (DUAL)   C16[(size_t)r * ldc + c] = f2b(v);
      }
    }
  }
}

// ---------------------------------------------------------------------------
// Bidirectional GRU scan. 16 blocks per direction; block b owns h-slice
// j in [32b, 32b+32), i.e. gate rows {32b+j, 512+32b+j, 1024+32b+j}:
// 96x512 weights (f16) in LDS. Cross-block per-step exchange via TAGGED
// 64-bit relaxed agent atomics: word = (tag=sidx+1)<<32 | f32bits(h).
// No fences, no separate flag, one coherent round-trip per step.
// X must be zeroed before each launch (tags).
// ---------------------------------------------------------------------------
__global__ __launch_bounds__(256) void k_gru(
    const float* __restrict__ w_hh_f, const float* __restrict__ w_hh_b,
    const float* __restrict__ b_hh_f, const float* __restrict__ b_hh_b,
    const float* __restrict__ gi_f, const float* __restrict__ gi_b,
    u64* __restrict__ X, float* __restrict__ ctx)
{
  __shared__ __align__(16) u16 wlds[96 * 512];   // f16 bits (96KB)
  __shared__ float bh[96];
  __shared__ float hfull[512];
  __shared__ float ghl[96];

  const int bid = blockIdx.x;
  const int dir = bid >> 4;
  const int b   = bid & 15;
  const int tid = threadIdx.x;
  const int lane = tid & 63, wv = tid >> 6;

  const float* w_hh = dir ? w_hh_b : w_hh_f;
  const float* b_hh = dir ? b_hh_b : b_hh_f;
  const float* gi = dir ? gi_b : gi_f;
  u64* myX = X + (size_t)dir * 128 * 512;

  for (int idx = tid; idx < 96 * 128; idx += 256) {   // weights f32 -> f16 LDS
    int gl = idx >> 7;
    int kc = (idx & 127) << 2;
    int g = 32 * b + (gl & 31) + ((gl >> 5) << 9);
    float4 wv4 = *(const float4*)(w_hh + (size_t)g * 512 + kc);
    u16 dst[4];
    _Float16 h0 = (_Float16)wv4.x; __builtin_memcpy(&dst[0], &h0, 2);
    _Float16 h1 = (_Float16)wv4.y; __builtin_memcpy(&dst[1], &h1, 2);
    _Float16 h2 = (_Float16)wv4.z; __builtin_memcpy(&dst[2], &h2, 2);
    _Float16 h3 = (_Float16)wv4.w; __builtin_memcpy(&dst[3], &h3, 2);
    *(uint2*)(wlds + gl * 512 + kc) = *(uint2*)dst;
  }
  if (tid < 96) {
    int g = 32 * b + (tid & 31) + ((tid >> 5) << 9);
    bh[tid] = b_hh[g];
  }
  for (int i = tid; i < 512; i += 256) hfull[i] = 0.f;
  __syncthreads();

  h16x2 hh[4];
  #pragma unroll
  for (int i = 0; i < 4; ++i) { hh[i][0] = (_Float16)0.f; hh[i][1] = (_Float16)0.f; }
  float hprev = 0.f;                    // tid<32: own h element
  const int jg = 32 * b + tid;          // valid for tid<32

  for (int sidx = 0; sidx < 128; ++sidx) {
    const int t = dir ? (127 - sidx) : sidx;

    // early-issue gi loads (latency hides under the dot phase)
    float gir = 0.f, giz = 0.f, gin = 0.f;
    if (tid < 32) {
      gir = gi[t * 1536 + jg];
      giz = gi[t * 1536 + 512 + jg];
      gin = gi[t * 1536 + 1024 + jg];
    }

    for (int gg = 0; gg < 24; ++gg) {        // wave wv handles gates wv*24..+24
      int gl = wv * 24 + gg;
      const h16x2* wp = (const h16x2*)(wlds + gl * 512 + lane * 8);
      float pp = 0.f;
      pp = __builtin_amdgcn_fdot2(wp[0], hh[0], pp, false);
      pp = __builtin_amdgcn_fdot2(wp[1], hh[1], pp, false);
      pp = __builtin_amdgcn_fdot2(wp[2], hh[2], pp, false);
      pp = __builtin_amdgcn_fdot2(wp[3], hh[3], pp, false);
      pp = wred_sum(pp);
      if (lane == 0) ghl[gl] = pp;
    }
    __syncthreads();

    if (tid < 32) {
      int j = tid;
      float ghr = ghl[j] + bh[j];
      float ghz = ghl[j + 32] + bh[j + 32];
      float ghn = ghl[j + 64] + bh[j + 64];
      float rr = 1.f / (1.f + __expf(-(gir + ghr)));
      float zz = 1.f / (1.f + __expf(-(giz + ghz)));
      float nn = tanhf(gin + rr * ghn);
      float h2v = (1.f - zz) * nn + zz * hprev;
      hprev = h2v;
      if (sidx == 0)   ctx[(dir ? 1536 : 0)    + jg] = h2v;
      if (sidx == 127) ctx[(dir ? 512  : 1024) + jg] = h2v;
      if (sidx < 127) {
        union { float f; unsigned u; } cv; cv.f = h2v;
        u64 pk = ((u64)(unsigned)(sidx + 1) << 32) | (u64)cv.u;
        __hip_atomic_store(&myX[(size_t)sidx * 512 + jg], pk,
                           __ATOMIC_RELAXED, __HIP_MEMORY_SCOPE_AGENT);
      }
    }

    if (sidx < 127) {
      const unsigned want = (unsigned)(sidx + 1);
      const u64* src = myX + (size_t)sidx * 512;
      int e0 = tid * 2;
      u64 v0, v1;
      do { v0 = __hip_atomic_load(&src[e0],     __ATOMIC_RELAXED, __HIP_MEMORY_SCOPE_AGENT); }
      while ((unsigned)(v0 >> 32) != want);
      do { v1 = __hip_atomic_load(&src[e0 + 1], __ATOMIC_RELAXED, __HIP_MEMORY_SCOPE_AGENT); }
      while ((unsigned)(v1 >> 32) != want);
      union { unsigned u; float f; } a0, a1;
      a0.u = (unsigned)v0; a1.u = (unsigned)v1;
      hfull[e0] = a0.f; hfull[e0 + 1] = a1.f;
      __syncthreads();
      #pragma unroll
      for (int i = 0; i < 4; ++i) {
        hh[i][0] = (_Float16)hfull[lane * 8 + 2 * i];
        hh[i][1] = (_Float16)hfull[lane * 8 + 2 * i + 1];
      }
    }
  }
}

// ---------------------------------------------------------------------------
// small kernels
// ---------------------------------------------------------------------------
__global__ __launch_bounds__(256) void k_softmax1(
    const float* __restrict__ scores, const int* __restrict__ conn, u16* __restrict__ attw)
{
  int p = blockIdx.x * 4 + (threadIdx.x >> 6);
  int lane = threadIdx.x & 63;
  float v0 = scores[(size_t)p * 128 + lane];
  float v1 = scores[(size_t)p * 128 + 64 + lane];
  int m0 = conn[(size_t)p * 128 + lane];
  int m1 = conn[(size_t)p * 128 + 64 + lane];
  float x0 = m0 > 0 ? v0 : -INFINITY;
  float x1 = m1 > 0 ? v1 : -INFINITY;
  float mx = wred_max(fmaxf(x0, x1));
  if (!(mx > -INFINITY)) mx = 0.f;
  float e0 = m0 > 0 ? __expf(v0 - mx) : 0.f;
  float e1 = m1 > 0 ? __expf(v1 - mx) : 0.f;
  float s = wred_sum(e0 + e1);
  float inv = 1.f / (s + 1e-6f);
  attw[(size_t)p * 128 + lane] = f2b(e0 * inv);
  attw[(size_t)p * 128 + 64 + lane] = f2b(e1 * inv);
}

__global__ __launch_bounds__(256) void k_transpose(const u16* __restrict__ in, u16* __restrict__ out)
{
  int idx = blockIdx.x * 256 + threadIdx.x;   // over 128*1024
  int r = idx >> 10, c = idx & 1023;
  out[c * 128 + r] = in[idx];
}

// G[i] = src16[idxs[i]] : bf16 row gather (1024 wide), 4096 rows.
__global__ __launch_bounds__(256) void k_gather(const int* __restrict__ idxs,
    const u16* __restrict__ src, u16* __restrict__ G)
{
  int g = blockIdx.x * 256 + threadIdx.x;    // over 4096*128 16B-chunks
  int row = g >> 7, c16 = g & 127;
  int sidx = idxs[row];
  *(uint4*)(G + (size_t)row * Hn + c16 * 8) =
      *(const uint4*)(src + (size_t)sidx * Hn + c16 * 8);
}

__global__ __launch_bounds__(256) void k_cvec(const float* __restrict__ att1W,
    const float* __restrict__ att1b, const float* __restrict__ ctx, float* __restrict__ cvec)
{
  int i = blockIdx.x * 4 + (threadIdx.x >> 6);
  int lane = threadIdx.x & 63;
  const float* wrow = att1W + (size_t)i * 4096 + 2048 + lane * 32;
  const float* cp = ctx + lane * 32;
  float acc = 0.f;
  #pragma unroll
  for (int k = 0; k < 32; ++k) acc += wrow[k] * cp[k];
  acc = wred_sum(acc);
  if (lane == 0) cvec[i] = acc + att1b[i];
}

// edge scores for relation chunk [cb, cb+rows): edges e=cb+i and e=Rn+cb+i.
__global__ __launch_bounds__(256) void k_edge_s(const int* __restrict__ rcm,
    const u16* __restrict__ U1, const u16* __restrict__ V1c, const float* __restrict__ cvec,
    const float* __restrict__ att2w, const float* __restrict__ att2b,
    float* __restrict__ sval, int cb, int rows)
{
  int idx = blockIdx.x * 4 + (threadIdx.x >> 6);   // [0, 2*rows)
  int lane = threadIdx.x & 63;
  int rL = idx < rows ? idx : idx - rows;
  int e = idx < rows ? cb + idx : Rn + cb + rL;
  int p = rcm[e];
  const u16* u = U1 + (size_t)p * Hn + lane * 16;
  const u16* v = V1c + (size_t)rL * Hn + lane * 16;
  const float* aw = att2w + lane * 16;
  const float* cv = cvec + lane * 16;
  float acc = 0.f;
  #pragma unroll
  for (int i = 0; i < 16; ++i) {
    float x = b2f(u[i]) + b2f(v[i]) + cv[i];
    acc += aw[i] * leaky(x);
  }
  acc = wred_sum(acc);
  if (lane == 0) sval[e] = acc + att2b[0];
}

__global__ __launch_bounds__(256) void k_cnt(const int* __restrict__ rcm, int* __restrict__ cnt)
{
  int e = blockIdx.x * 256 + threadIdx.x;
  if (e < Rn && rcm[e] == rcm[Rn + e]) return;   // duplicate cell: obj copy wins
  atomicAdd(cnt + rcm[e], 1);
}

__global__ __launch_bounds__(256) void k_scan(const int* __restrict__ cnt,
    int* __restrict__ offs, int* __restrict__ cursor)
{
  __shared__ int part[256];
  __shared__ int pscan[256];
  int tid = threadIdx.x;
  int loc[16]; int s = 0;
  #pragma unroll
  for (int i = 0; i < 16; ++i) { loc[i] = cnt[tid * 16 + i]; s += loc[i]; }
  part[tid] = s; __syncthreads();
  if (tid == 0) { int a = 0; for (int i = 0; i < 256; ++i) { pscan[i] = a; a += part[i]; } }
  __syncthreads();
  int base = pscan[tid];
  #pragma unroll
  for (int i = 0; i < 16; ++i) { offs[tid * 16 + i] = base; cursor[tid * 16 + i] = base; base += loc[i]; }
  if (tid == 255) offs[Pn] = base;
}

__global__ __launch_bounds__(256) void k_fill(const int* __restrict__ rcm,
    const float* __restrict__ sval, int* __restrict__ cursor,
    int* __restrict__ er, float* __restrict__ es)
{
  int e = blockIdx.x * 256 + threadIdx.x;
  if (e < Rn && rcm[e] == rcm[Rn + e]) return;
  int slot = atomicAdd(cursor + rcm[e], 1);
  er[slot] = e & (Rn - 1);
  es[slot] = sval[e];
}

__global__ __launch_bounds__(256) void k_att_apply(const int* __restrict__ offs,
    const int* __restrict__ er, const float* __restrict__ es,
    const float* __restrict__ urel, u16* __restrict__ pacc)
{
  int p = blockIdx.x;
  int tid = threadIdx.x;
  int beg = offs[p], end = offs[p + 1];
  float mx = -INFINITY;
  for (int i = beg; i < end; ++i) mx = fmaxf(mx, es[i]);
  float den = 1e-6f;
  for (int i = beg; i < end; ++i) den += __expf(es[i] - mx);
  float inv = 1.f / den;
  float a0 = 0.f, a1 = 0.f, a2 = 0.f, a3 = 0.f;
  int c0 = tid * 4;
  for (int i = beg; i < end; ++i) {
    float wgt = __expf(es[i] - mx) * inv;
    float4 q = *(const float4*)(urel + (size_t)er[i] * Hn + c0);
    a0 += wgt * q.x; a1 += wgt * q.y; a2 += wgt * q.z; a3 += wgt * q.w;
  }
  ushort4 ov; ov.x = f2b(a0); ov.y = f2b(a1); ov.z = f2b(a2); ov.w = f2b(a3);
  *(ushort4*)(pacc + (size_t)p * Hn + c0) = ov;
}

// ---------------------------------------------------------------------------
extern "C" void kernel_launch(void* const* d_in, const int* in_sizes, int n_in,
                              void* d_out, int out_size, void* d_ws, size_t ws_size,
                              hipStream_t stream)
{
  // ALL float tensors are float32 (reference dtype); bf16 only internally.
  const float* word_feat   = (const float*)d_in[0];
  const float* phrase_feat = (const float*)d_in[1];
  const float* rel_feat    = (const float*)d_in[2];
  const float* w_ih_f = (const float*)d_in[3];
  const float* w_hh_f = (const float*)d_in[4];
  const float* b_ih_f = (const float*)d_in[5];
  const float* b_hh_f = (const float*)d_in[6];
  const float* w_ih_b = (const float*)d_in[7];
  const float* w_hh_b = (const float*)d_in[8];
  const float* b_ih_b = (const float*)d_in[9];
  const float* b_hh_b = (const float*)d_in[10];
  const float* w2p_w_W = (const float*)d_in[11];
  const float* w2p_w_b = (const float*)d_in[12];
  const float* w2p_p_W = (const float*)d_in[13];
  const float* w2p_p_b = (const float*)d_in[14];
  const float* w2p_t_W = (const float*)d_in[15];
  const float* w2p_t_b = (const float*)d_in[16];
  const float* rel_W   = (const float*)d_in[17];
  const float* rel_b   = (const float*)d_in[18];
  const float* att1_W  = (const float*)d_in[19];
  const float* att1_b  = (const float*)d_in[20];
  const float* att2_W  = (const float*)d_in[21];
  const float* att2_b  = (const float*)d_in[22];
  const float* r2p_t_W = (const float*)d_in[23];
  const float* r2p_t_b = (const float*)d_in[24];
  const int* rcm  = (const int*)d_in[25];
  const int* conn = (const int*)d_in[26];

  float* out_word = (float*)d_out;
  float* out_phr  = out_word + (size_t)Wn * Hn;   // 4096x1024 f32
  float* out_urel = out_phr + (size_t)Pn * Hn;    // 8192x1024 f32

  // ---- workspace (~44 MB, static layout with phase-disjoint unions) ----
  char* ws = (char*)d_ws;
  size_t off = 0;
  auto alloc = [&](size_t bytes) -> char* {
    char* pptr = ws + off; off += (bytes + 255) & ~(size_t)255; return pptr;
  };
  int*   cnt    = (int*)alloc(Pn * 4);                    // zeroed below
  u64*   X      = (u64*)alloc(2 * 128 * 512 * 8);         // GRU exchange, zeroed
  float* ctx    = (float*)alloc(2048 * 4);
  float* cvec   = (float*)alloc(1024 * 4);
  int*   cursor = (int*)alloc(Pn * 4);
  int*   offs   = (int*)alloc((Pn + 1) * 4);
  int*   er     = (int*)alloc(2 * Rn * 4);
  float* es     = (float*)alloc(2 * Rn * 4);
  float* sval   = (float*)alloc(2 * Rn * 4);
  u16*   wf16   = (u16*)alloc((size_t)Wn * Hn * 2);       // 0.26MB
  u16*   wl     = (u16*)alloc((size_t)Wn * Hn * 2);       // 0.26MB
  u16*   upd16  = (u16*)alloc((size_t)Pn * Hn * 2);       // 8.39MB
  char*  RA     = alloc(16777216);                        // P3 / P5 union
  u16*   W1s    = (u16*)RA;                               // 2.10MB (P3)
  u16*   W2s    = (u16*)(RA + 2097152);                   // 2.10MB (P3)
  u16*   W3s    = (u16*)(RA + 4194304);                   // 2.10MB (P3)
  u16*   G      = (u16*)(RA + 6291456);                   // 8.39MB (P3)
  u16*   rf16c  = (u16*)(RA + 14680064);                  // 2.10MB (P3)
  u16*   pacc   = (u16*)RA;                               // 8.39MB (P5)
  u16*   r2pW16 = (u16*)(RA + 8388608);                   // 2.10MB (P5)
  u16*   A1p16  = (u16*)alloc(2097152);
  u16*   A1r16  = (u16*)alloc(2097152);
  u16*   U1     = (u16*)alloc((size_t)Pn * Hn * 2);       // 8.39MB
  u16*   urelc  = (u16*)alloc(2097152);
  u16*   V1c    = (u16*)alloc(2097152);

  // ---- d_out f32 regions as early-phase scratch ----
  char* phrB = (char*)out_phr;          // 16.78MB, free until upd write
  float* scores = (float*)phrB;                         // 2.10MB
  u16*   wih16f = (u16*)(phrB + 2097152);               // 3.15MB
  u16*   wih16b = (u16*)(phrB + 5242880);               // 3.15MB
  float* gi_f   = (float*)(phrB + 8388608);             // 0.79MB
  float* gi_b   = (float*)(phrB + 9175040);             // 0.79MB
  char* urlB = (char*)out_urel;         // 33.55MB, free until urel writes
  u16*   pf16   = (u16*)urlB;                           // 8.39MB
  u16*   w2pw16 = (u16*)(urlB + 8388608);               // 2.10MB
  u16*   w2pp16 = (u16*)(urlB + 10485760);              // 2.10MB
  u16*   w2pt16 = (u16*)(urlB + 12582912);              // 2.10MB
  u16*   pl     = (u16*)(urlB + 14680064);              // 8.39MB
  u16*   aw     = (u16*)(urlB + 23068672);              // 8.39MB
  u16*   attw   = (u16*)(urlB + 31457280);              // 1.05MB
  u16*   wfT    = (u16*)(urlB + 32505856);              // 0.26MB

  // zero cnt + X (contiguous)
  (void)hipMemsetAsync(cnt, 0, Pn * 4 + 2 * 128 * 512 * 8, stream);

  dim3 blk(256);

  // P1: GRU. Convert word/w_ih to bf16, gi GEMMs (f32 out), then the scan.
  k_cvt<<<64, blk, 0, stream>>>(word_feat, Hn, wf16);
  k_cvt<<<768, blk, 0, stream>>>(w_ih_f, Hn, wih16f);
  k_cvt<<<768, blk, 0, stream>>>(w_ih_b, Hn, wih16b);
  k_gemm_bt<true, false, true, false, false><<<dim3(12, 1), blk, 0, stream>>>(
      wf16, Hn, wih16f, Hn, gi_f, 1536, b_ih_f, nullptr, 0, nullptr, 1.f, Hn);
  k_gemm_bt<true, false, true, false, false><<<dim3(12, 1), blk, 0, stream>>>(
      wf16, Hn, wih16b, Hn, gi_b, 1536, b_ih_b, nullptr, 0, nullptr, 1.f, Hn);
  k_gru<<<32, blk, 0, stream>>>(w_hh_f, w_hh_b, b_hh_f, b_hh_b, gi_f, gi_b, X, ctx);

  // P2: word->phrase attention; upd (f32 in out_phr + bf16 copy).
  k_cvt<<<2048, blk, 0, stream>>>(phrase_feat, Hn, pf16);
  k_cvt<<<512, blk, 0, stream>>>(w2p_w_W, Hn, w2pw16);
  k_cvt<<<512, blk, 0, stream>>>(w2p_p_W, Hn, w2pp16);
  k_cvt<<<512, blk, 0, stream>>>(w2p_t_W, Hn, w2pt16);
  k_gemm_bt<false, true, true, false, false><<<dim3(8, 1), blk, 0, stream>>>(
      wf16, Hn, w2pw16, Hn, wl, Hn, w2p_w_b, nullptr, 0, nullptr, 1.f, Hn);
  k_gemm_bt<false, true, true, false, false><<<dim3(8, 32), blk, 0, stream>>>(
      pf16, Hn, w2pp16, Hn, pl, Hn, w2p_p_b, nullptr, 0, nullptr, 1.f, Hn);
  k_gemm_bt<true, false, false, false, false><<<dim3(1, 32), blk, 0, stream>>>(
      pl, Hn, wl, Hn, scores, Wn, nullptr, nullptr, 0, nullptr, 0.03125f, Hn);
  k_softmax1<<<Pn / 4, blk, 0, stream>>>(scores, conn, attw);
  k_transpose<<<(Wn * Hn) / 256, blk, 0, stream>>>(wf16, wfT);
  k_gemm_bt<false, false, false, false, false><<<dim3(8, 32), blk, 0, stream>>>(
      attw, Wn, wfT, Wn, aw, Hn, nullptr, nullptr, 0, nullptr, 1.f, Wn);
  k_gemm_bt<true, false, true, true, true><<<dim3(8, 32), blk, 0, stream>>>(
      aw, Hn, w2pt16, Hn, out_phr, Hn, w2p_t_b, phrase_feat, Hn, upd16, 1.f, Hn);

  // P3: urel (f32 in out_urel) = rel_feat@W3' + upd[sub]@W1' + upd[obj]@W2' + b
  k_cvt<<<512, blk, 0, stream>>>(rel_W, 3 * Hn, W1s);
  k_cvt<<<512, blk, 0, stream>>>(rel_W + Hn, 3 * Hn, W2s);
  k_cvt<<<512, blk, 0, stream>>>(rel_W + 2 * Hn, 3 * Hn, W3s);
  for (int cb = 0; cb < Rn; cb += 1024) {
    k_cvt<<<512, blk, 0, stream>>>(rel_feat + (size_t)cb * Hn, Hn, rf16c);
    k_gemm_bt<true, false, true, false, false><<<dim3(8, 8), blk, 0, stream>>>(
        rf16c, Hn, W3s, Hn, out_urel + (size_t)cb * Hn, Hn, rel_b, nullptr, 0,
        nullptr, 1.f, Hn);
  }
  for (int h = 0; h < 2; ++h) {
    float* Ch = out_urel + (size_t)h * 4096 * Hn;
    k_gather<<<2048, blk, 0, stream>>>(rcm + h * 4096, upd16, G);
    k_gemm_bt<true, false, false, true, false><<<dim3(8, 32), blk, 0, stream>>>(
        G, Hn, W1s, Hn, Ch, Hn, nullptr, Ch, Hn, nullptr, 1.f, Hn);
    k_gather<<<2048, blk, 0, stream>>>(rcm + Rn + h * 4096, upd16, G);
    k_gemm_bt<true, false, false, true, false><<<dim3(8, 32), blk, 0, stream>>>(
        G, Hn, W2s, Hn, Ch, Hn, nullptr, Ch, Hn, nullptr, 1.f, Hn);
  }

  // P4: edge scores s = att2 . leaky(U1[p] + V1[r] + cvec)
  k_cvt<<<512, blk, 0, stream>>>(att1_W, 4 * Hn, A1p16);
  k_cvt<<<512, blk, 0, stream>>>(att1_W + Hn, 4 * Hn, A1r16);
  k_gemm_bt<false, false, false, false, false><<<dim3(8, 32), blk, 0, stream>>>(
      upd16, Hn, A1p16, Hn, U1, Hn, nullptr, nullptr, 0, nullptr, 1.f, Hn);
  k_cvec<<<256, blk, 0, stream>>>(att1_W, att1_b, ctx, cvec);
  for (int cb = 0; cb < Rn; cb += 1024) {
    k_cvt<<<512, blk, 0, stream>>>(out_urel + (size_t)cb * Hn, Hn, urelc);
    k_gemm_bt<false, false, false, false, false><<<dim3(8, 8), blk, 0, stream>>>(
        urelc, Hn, A1r16, Hn, V1c, Hn, nullptr, nullptr, 0, nullptr, 1.f, Hn);
    k_edge_s<<<512, blk, 0, stream>>>(rcm, U1, V1c, cvec, att2_W, att2_b, sval, cb, 1024);
  }

  // P5: CSR + masked softmax + att@urel; final residual GEMM in-place.
  k_cnt<<<(2 * Rn) / 256, blk, 0, stream>>>(rcm, cnt);
  k_scan<<<1, blk, 0, stream>>>(cnt, offs, cursor);
  k_fill<<<(2 * Rn) / 256, blk, 0, stream>>>(rcm, sval, cursor, er, es);
  k_att_apply<<<Pn, blk, 0, stream>>>(offs, er, es, out_urel, pacc);
  k_cvt<<<512, blk, 0, stream>>>(r2p_t_W, Hn, r2pW16);
  k_gemm_bt<true, false, true, true, false><<<dim3(8, 32), blk, 0, stream>>>(
      pacc, Hn, r2pW16, Hn, out_phr, Hn, r2p_t_b, out_phr, Hn, nullptr, 1.f, Hn);

  // word_feat passthrough (f32)
  (void)hipMemcpyAsync(out_word, word_feat, (size_t)Wn * Hn * 4,
                       hipMemcpyDeviceToDevice, stream);
}